// Round 1
// baseline (571.488 us; speedup 1.0000x reference)
//
#include <hip/hip_runtime.h>

// SpanMaxPooler: B=32, S=4096, H=1024, K=2
// out[b, k*H + h] = max over s in [start[b,k], end[b,k]) of hidden[b,s,h],
//                   or missing_embeddings[k,h] if span missing (start<0 || end<0).

#define B_ 32
#define S_ 4096
#define H_ 1024
#define K_ 2
#define CHUNKS 4   // H split into 4 chunks of 256 cols -> 256 blocks total
#define NEG_INF (-3.4028234663852886e38f)

__global__ __launch_bounds__(256) void span_max_kernel(
    const float* __restrict__ hidden,   // [B,S,H]
    const int*   __restrict__ start,    // [B,K]
    const int*   __restrict__ end,      // [B,K]
    const float* __restrict__ miss,     // [K,H]
    float*       __restrict__ out) {    // [B,K*H]
  const int blk   = blockIdx.x;
  const int chunk = blk & (CHUNKS - 1);
  const int bk    = blk >> 2;            // = b*K + k
  const int k     = bk & (K_ - 1);
  const int b     = bk >> 1;

  const int wave = threadIdx.x >> 6;     // 0..3 (row groups)
  const int lane = threadIdx.x & 63;
  const int col  = chunk * 256 + lane * 4;

  const int st = start[bk];
  const int en = end[bk];

  float* outp = out + (size_t)bk * H_ + col;   // bk*H == b*K*H + k*H

  if (st < 0 || en < 0) {
    // block-uniform branch: whole block takes it, no barrier divergence
    if (wave == 0) {
      const float4 m = *(const float4*)(miss + (size_t)k * H_ + col);
      *(float4*)outp = m;
    }
    return;
  }

  float4 acc = make_float4(NEG_INF, NEG_INF, NEG_INF, NEG_INF);
  const float* base = hidden + (size_t)b * S_ * H_ + col;
  for (int s = st + wave; s < en; s += 4) {
    const float4 v = *(const float4*)(base + (size_t)s * H_);
    acc.x = fmaxf(acc.x, v.x);
    acc.y = fmaxf(acc.y, v.y);
    acc.z = fmaxf(acc.z, v.z);
    acc.w = fmaxf(acc.w, v.w);
  }

  __shared__ float4 red[256];
  red[threadIdx.x] = acc;
  __syncthreads();

  if (wave == 0) {
    float4 a = red[lane];
    const float4 p = red[64 + lane];
    const float4 q = red[128 + lane];
    const float4 r = red[192 + lane];
    a.x = fmaxf(fmaxf(a.x, p.x), fmaxf(q.x, r.x));
    a.y = fmaxf(fmaxf(a.y, p.y), fmaxf(q.y, r.y));
    a.z = fmaxf(fmaxf(a.z, p.z), fmaxf(q.z, r.z));
    a.w = fmaxf(fmaxf(a.w, p.w), fmaxf(q.w, r.w));
    *(float4*)outp = a;
  }
}

extern "C" void kernel_launch(void* const* d_in, const int* in_sizes, int n_in,
                              void* d_out, int out_size, void* d_ws, size_t ws_size,
                              hipStream_t stream) {
  const float* hidden = (const float*)d_in[0];
  const int*   start  = (const int*)d_in[1];
  const int*   end    = (const int*)d_in[2];
  const float* miss   = (const float*)d_in[3];
  float*       out    = (float*)d_out;

  dim3 grid(B_ * K_ * CHUNKS);
  dim3 block(256);
  span_max_kernel<<<grid, block, 0, stream>>>(hidden, start, end, miss, out);
}